// Round 7
// baseline (157.874 us; speedup 1.0000x reference)
//
#include <hip/hip_runtime.h>
#include <hip/hip_bf16.h>

#define NB 16384        // rows (B)
#define NC 1000         // classes (C)
#define NV 250          // float4 per row
#define CHUNKS 5        // column chunks for transposed argmax
#define F4C 50          // float4 per chunk (5*50*4 = 1000 cols exactly)
#define NW_B 4096       // hinge-kernel waves, 4 rows each

// ---- Kernel A3: transposed argmax. Wave = 64 rows x 1 chunk. Zero cross-lane.
// pairs[chunk*NB + row] = (maxval, bits(idx)) over that chunk's 200 columns.
__global__ __launch_bounds__(256) void argmax_t_kernel(
        const float* __restrict__ target,
        float2* __restrict__ pairs) {
    const int t    = threadIdx.x;
    const int wave = t >> 6;
    const int lane = t & 63;
    const int W    = blockIdx.x * 4 + wave;   // 0..1279
    const int rowblk = W & 255;               // 0..255
    const int chunk  = W >> 8;                // 0..4
    const int row    = rowblk * 64 + lane;

    const float4* __restrict__ b4 =
        (const float4*)(target + (size_t)row * NC + chunk * (F4C * 4));
    const int jbase = chunk * (F4C * 4);

    // 4 independent trackers (one per float4 component) -> 4x ILP on the chain
    float vx = -INFINITY, vy = -INFINITY, vz = -INFINITY, vw = -INFINITY;
    int   ix = 0, iy = 0, iz = 0, iw = 0;

    #pragma unroll 10
    for (int it = 0; it < F4C; ++it) {
        const float4 v = b4[it];
        const int j = jbase + it * 4;
        if (v.x > vx) { vx = v.x; ix = j; }
        if (v.y > vy) { vy = v.y; iy = j + 1; }
        if (v.z > vz) { vz = v.z; iz = j + 2; }
        if (v.w > vw) { vw = v.w; iw = j + 3; }
    }
    // merge trackers; exact first-index tie-break
    float bv = vx; int bi = ix;
    if (vy > bv || (vy == bv && iy < bi)) { bv = vy; bi = iy; }
    if (vz > bv || (vz == bv && iz < bi)) { bv = vz; bi = iz; }
    if (vw > bv || (vw == bv && iw < bi)) { bv = vw; bi = iw; }

    pairs[chunk * NB + row] = make_float2(bv, __int_as_float(bi));
}

// ---- Kernel C3: combine 5 chunk-partials per row, gather x1, write labx1.
__global__ __launch_bounds__(256) void combine_kernel(
        const float2* __restrict__ pairs,
        const float* __restrict__ logits,
        float2* __restrict__ labx1) {
    const int row = blockIdx.x * 256 + threadIdx.x;

    float2 p = pairs[row];
    float bv = p.x;
    int   bi = __float_as_int(p.y);
    #pragma unroll
    for (int c = 1; c < CHUNKS; ++c) {
        float2 q = pairs[c * NB + row];
        // higher chunk => strictly larger indices, so '>' alone preserves
        // first-index tie-break across chunks.
        if (q.x > bv) { bv = q.x; bi = __float_as_int(q.y); }
    }
    const float x1 = logits[(size_t)row * NC + bi];
    labx1[row] = make_float2(__int_as_float(bi), x1);
}

// ---- Kernel B: 4 rows per wave, pure streaming hinge sum (round-6 version).
__global__ __launch_bounds__(256) void loss_kernel(
        const float* __restrict__ logits,
        const float2* __restrict__ labx1,
        float* __restrict__ partial) {
    const int t    = threadIdx.x;
    const int wave = t >> 6;
    const int lane = t & 63;
    const int w    = blockIdx.x * 4 + wave;   // 0..4095
    const int row0 = w * 4;

    const int  i0 = lane;
    const int  i1 = 64 + lane;
    const int  i2 = 128 + lane;
    const int  i3 = (192 + lane < NV) ? (192 + lane) : (NV - 1);
    const bool v3w = (192 + lane) < NV;
    const float inv_pos = 1.0f / (float)(NC - 1);

    const float4* __restrict__ r0 = (const float4*)(logits + (size_t)(row0 + 0) * NC);
    const float4* __restrict__ r1 = (const float4*)(logits + (size_t)(row0 + 1) * NC);
    const float4* __restrict__ r2 = (const float4*)(logits + (size_t)(row0 + 2) * NC);
    const float4* __restrict__ r3 = (const float4*)(logits + (size_t)(row0 + 3) * NC);
    float4 a0 = r0[i0], a1 = r0[i1], a2 = r0[i2], a3 = r0[i3];
    float4 b0 = r1[i0], b1 = r1[i1], b2 = r1[i2], b3 = r1[i3];
    float4 c0 = r2[i0], c1 = r2[i1], c2 = r2[i2], c3 = r2[i3];
    float4 d0 = r3[i0], d1 = r3[i1], d2 = r3[i2], d3 = r3[i3];

    const float2 p0 = labx1[row0 + 0];
    const float2 p1 = labx1[row0 + 1];
    const float2 p2 = labx1[row0 + 2];
    const float2 p3 = labx1[row0 + 3];

    float sum = 0.0f;

#define HINGE_F4(V, BASE, LABEL, X1)                                                      \
    {                                                                                     \
        const int base_ = (BASE);                                                         \
        {                                                                                 \
            float m0 = (base_ == 0) ? 1.0f : fabsf((float)((LABEL) - base_)) * inv_pos;   \
            sum += fmaxf(V.x - (X1) + m0, 0.0f);                                          \
        }                                                                                 \
        sum += fmaxf(V.y - (X1) + fabsf((float)((LABEL) - (base_ + 1))) * inv_pos, 0.0f); \
        sum += fmaxf(V.z - (X1) + fabsf((float)((LABEL) - (base_ + 2))) * inv_pos, 0.0f); \
        sum += fmaxf(V.w - (X1) + fabsf((float)((LABEL) - (base_ + 3))) * inv_pos, 0.0f); \
    }

#define HROW(V0, V1, V2, V3, P)                                      \
    {                                                                \
        const int   label = __float_as_int(P.x);                     \
        const float x1    = P.y;                                     \
        if (label != 0) {   /* wave-uniform branch */                \
            HINGE_F4(V0, i0 * 4, label, x1)                          \
            HINGE_F4(V1, i1 * 4, label, x1)                          \
            HINGE_F4(V2, i2 * 4, label, x1)                          \
            if (v3w) HINGE_F4(V3, i3 * 4, label, x1)                 \
        }                                                            \
    }

    HROW(a0, a1, a2, a3, p0)
    HROW(b0, b1, b2, b3, p1)
    HROW(c0, c1, c2, c3, p2)
    HROW(d0, d1, d2, d3, p3)
#undef HROW
#undef HINGE_F4

    #pragma unroll
    for (int off = 32; off > 0; off >>= 1)
        sum += __shfl_down(sum, off, 64);

    if (lane == 0)
        partial[w] = sum * (1.0f / (float)NB);
}

// ---- Reduce 4096 partials -> out[0].
__global__ __launch_bounds__(256) void reduce_partials_kernel(
        const float* __restrict__ partial,
        float* __restrict__ out) {
    const int t    = threadIdx.x;
    const int wave = t >> 6;
    const int lane = t & 63;

    float sum = 0.0f;
    const float4* p4 = (const float4*)partial;   // 1024 float4
    #pragma unroll
    for (int i = 0; i < 4; ++i) {
        float4 v = p4[t + i * 256];
        sum += (v.x + v.y) + (v.z + v.w);
    }
    #pragma unroll
    for (int off = 32; off > 0; off >>= 1)
        sum += __shfl_down(sum, off, 64);

    __shared__ float s_sum[4];
    if (lane == 0) s_sum[wave] = sum;
    __syncthreads();
    if (t == 0)
        out[0] = s_sum[0] + s_sum[1] + s_sum[2] + s_sum[3];
}

extern "C" void kernel_launch(void* const* d_in, const int* in_sizes, int n_in,
                              void* d_out, int out_size, void* d_ws, size_t ws_size,
                              hipStream_t stream) {
    const float* logits = (const float*)d_in[0];
    const float* target = (const float*)d_in[1];
    float* out = (float*)d_out;

    float2* labx1   = (float2*)d_ws;                             // 128 KB
    float2* pairs   = (float2*)((char*)d_ws + (size_t)NB * 8);   // 5*128 KB = 640 KB
    float*  partial = (float*)((char*)d_ws + (size_t)NB * 8 * (1 + CHUNKS)); // 16 KB

    argmax_t_kernel<<<(256 * CHUNKS) / 4, 256, 0, stream>>>(target, pairs);
    combine_kernel<<<NB / 256, 256, 0, stream>>>(pairs, logits, labx1);
    loss_kernel<<<NW_B / 4, 256, 0, stream>>>(logits, labx1, partial);
    reduce_partials_kernel<<<1, 256, 0, stream>>>(partial, out);
}